// Round 2
// baseline (1396.035 us; speedup 1.0000x reference)
//
#include <hip/hip_runtime.h>

#define N_NODES 50000
#define N_EDGES 800000
#define HID 128
#define OUT_CH 64

// ---------------- graph preprocessing ----------------

__global__ void deg_init(float* __restrict__ deg, float* __restrict__ sum) {
    int i = blockIdx.x * blockDim.x + threadIdx.x;
    if (i < N_NODES) deg[i] = 1.0f;  // self-loop
    if (i < OUT_CH) sum[i] = 0.0f;
}

__global__ void deg_accum(const int* __restrict__ ei, float* __restrict__ deg) {
    int e = blockIdx.x * blockDim.x + threadIdx.x;
    if (e < N_EDGES) atomicAdd(&deg[ei[N_EDGES + e]], 1.0f);  // target
}

__global__ void dinv_kernel(float* __restrict__ deg) {
    int i = blockIdx.x * blockDim.x + threadIdx.x;
    if (i < N_NODES) deg[i] = rsqrtf(deg[i]);  // deg >= 1 always
}

__global__ void norm_kernel(const int* __restrict__ ei, const float* __restrict__ dinv,
                            float* __restrict__ norm) {
    int e = blockIdx.x * blockDim.x + threadIdx.x;
    if (e < N_EDGES) norm[e] = dinv[ei[e]] * dinv[ei[N_EDGES + e]];
}

// ---------------- dense GEMM: Y[n][OUT] = X[n][128] @ W[128][OUT] (+bias) ----------------

template <int OUT, bool ADD_BIAS>
__global__ __launch_bounds__(256)
void gemm128(const float* __restrict__ X, const float* __restrict__ W,
             const float* __restrict__ bias, float* __restrict__ Y, int n) {
    constexpr int ROWS = 32;
    __shared__ float Wl[128 * OUT];
    __shared__ float Xl[ROWS * 128];
    const int tid = threadIdx.x;
    const int r0 = blockIdx.x * ROWS;

    for (int i = tid; i < 128 * OUT; i += 256) Wl[i] = W[i];
    for (int i = tid; i < ROWS * 128; i += 256) {
        int r = r0 + (i >> 7);
        Xl[i] = (r < n) ? X[r0 * 128 + i] : 0.0f;
    }
    __syncthreads();

    constexpr int RG = 256 / OUT;   // row groups per block of threads
    constexpr int PR = ROWS / RG;   // rows per thread
    const int colc = tid % OUT;
    const int rb = tid / OUT;

    float acc[PR];
#pragma unroll
    for (int i = 0; i < PR; i++) acc[i] = 0.0f;

    for (int k = 0; k < 128; k++) {
        float wv = Wl[k * OUT + colc];
#pragma unroll
        for (int i = 0; i < PR; i++) acc[i] += Xl[(rb + i * RG) * 128 + k] * wv;
    }

    float bv = ADD_BIAS ? bias[colc] : 0.0f;
#pragma unroll
    for (int i = 0; i < PR; i++) {
        int r = r0 + rb + i * RG;
        if (r < n) Y[r * OUT + colc] = acc[i] + bv;
    }
}

// ---------------- aggregation ----------------

// out[i][:] = t[i][:] * dinv[i]^2   (self-loop term; also fully initializes out)
__global__ void selfloop_init(const float* __restrict__ t, const float* __restrict__ dinv,
                              float* __restrict__ out) {
    int g = blockIdx.x * blockDim.x + threadIdx.x;
    if (g < N_NODES * HID) {
        float d = dinv[g >> 7];
        out[g] = t[g] * d * d;
    }
}

// per-edge: out[col][f] += t[row][f] * norm[e], one feature per thread
__global__ void scatter_edges(const float* __restrict__ t, const int* __restrict__ ei,
                              const float* __restrict__ norm, float* __restrict__ out) {
    int g = blockIdx.x * blockDim.x + threadIdx.x;
    int f = g & 127;
    int e = g >> 7;
    int estride = (gridDim.x * blockDim.x) >> 7;
    for (; e < N_EDGES; e += estride) {
        int r = ei[e];
        int c = ei[N_EDGES + e];
        float v = t[r * HID + f] * norm[e];
        atomicAdd(&out[c * HID + f], v);
    }
}

__global__ void bias_relu(float* __restrict__ h, const float* __restrict__ b) {
    int g = blockIdx.x * blockDim.x + threadIdx.x;
    if (g < N_NODES * HID) {
        float v = h[g] + b[g & 127];
        h[g] = v > 0.0f ? v : 0.0f;
    }
}

// ---------------- mean pool ----------------

__global__ __launch_bounds__(256)
void mean_partial(const float* __restrict__ P, float* __restrict__ sum) {
    __shared__ float red[256];
    const int tid = threadIdx.x;
    const int c = tid & 63;
    const int grp = tid >> 6;
    float acc = 0.0f;
    for (int r = blockIdx.x * 4 + grp; r < N_NODES; r += gridDim.x * 4)
        acc += P[r * OUT_CH + c];
    red[tid] = acc;
    __syncthreads();
    if (grp == 0) {
        float s = red[c] + red[64 + c] + red[128 + c] + red[192 + c];
        atomicAdd(&sum[c], s);
    }
}

__global__ void mean_final(const float* __restrict__ sum, float* __restrict__ out) {
    int j = threadIdx.x;
    if (j < OUT_CH) out[N_NODES * OUT_CH + j] = sum[j] * (1.0f / N_NODES);
}

// ---------------- launch ----------------

extern "C" void kernel_launch(void* const* d_in, const int* in_sizes, int n_in,
                              void* d_out, int out_size, void* d_ws, size_t ws_size,
                              hipStream_t stream) {
    const float* x  = (const float*)d_in[0];
    const int* ei   = (const int*)d_in[1];   // int32 on device (harness converts)
    const float* W1 = (const float*)d_in[2];
    const float* b1 = (const float*)d_in[3];
    const float* W2 = (const float*)d_in[4];
    const float* b2 = (const float*)d_in[5];
    const float* W3 = (const float*)d_in[6];
    const float* b3 = (const float*)d_in[7];
    const float* Wo = (const float*)d_in[8];
    const float* bo = (const float*)d_in[9];
    float* out = (float*)d_out;

    char* ws = (char*)d_ws;
    auto take = [&](size_t bytes) {
        char* p = ws;
        ws += (bytes + 255) & ~size_t(255);
        return (void*)p;
    };
    float* deg  = (float*)take((size_t)N_NODES * 4);          // becomes dinv in place
    float* norm = (float*)take((size_t)N_EDGES * 4);
    float* sum  = (float*)take(OUT_CH * 4);
    float* hA   = (float*)take((size_t)N_NODES * HID * 4);
    float* hB   = (float*)take((size_t)N_NODES * HID * 4);

    const int BS = 256;
    const int gN   = (N_NODES + BS - 1) / BS;
    const int gE   = (N_EDGES + BS - 1) / BS;
    const int gNH  = (N_NODES * HID + BS - 1) / BS;
    const int gGemm = (N_NODES + 31) / 32;

    // graph setup
    deg_init<<<gN, BS, 0, stream>>>(deg, sum);
    deg_accum<<<gE, BS, 0, stream>>>(ei, deg);
    dinv_kernel<<<gN, BS, 0, stream>>>(deg);
    norm_kernel<<<gE, BS, 0, stream>>>(ei, deg, norm);

    const float* hin = x;
    const float* Ws[3] = {W1, W2, W3};
    const float* bs[3] = {b1, b2, b3};
    for (int layer = 0; layer < 3; layer++) {
        gemm128<HID, false><<<gGemm, BS, 0, stream>>>(hin, Ws[layer], nullptr, hA, N_NODES);
        selfloop_init<<<gNH, BS, 0, stream>>>(hA, deg, hB);
        scatter_edges<<<4096, BS, 0, stream>>>(hA, ei, norm, hB);
        bias_relu<<<gNH, BS, 0, stream>>>(hB, bs[layer]);
        hin = hB;
    }

    // output projection straight into d_out, then mean pool
    gemm128<OUT_CH, true><<<gGemm, BS, 0, stream>>>(hB, Wo, bo, out, N_NODES);
    mean_partial<<<256, BS, 0, stream>>>(out, sum);
    mean_final<<<1, 64, 0, stream>>>(sum, out);
}

// Round 3
// 564.734 us; speedup vs baseline: 2.4720x; 2.4720x over previous
//
#include <hip/hip_runtime.h>

#define N_NODES 50000
#define N_EDGES 800000
#define HID 128
#define OUT_CH 64
#define NB_SCAN 196   // ceil(50000/256)

// ---------------- CSR construction ----------------

__global__ void prep_init(int* __restrict__ counts, float* __restrict__ sum) {
    int i = blockIdx.x * blockDim.x + threadIdx.x;
    if (i < N_NODES) counts[i] = 0;
    if (i < OUT_CH) sum[i] = 0.0f;
}

__global__ void count_edges(const int* __restrict__ ei, int* __restrict__ counts) {
    int e = blockIdx.x * blockDim.x + threadIdx.x;
    if (e < N_EDGES) atomicAdd(&counts[ei[N_EDGES + e]], 1);  // target
}

// block-level exclusive scan of counts -> row_start, block totals -> bsum
__global__ __launch_bounds__(256)
void scan_blocks(const int* __restrict__ counts, int* __restrict__ row_start,
                 int* __restrict__ bsum) {
    __shared__ int s[256];
    int tid = threadIdx.x;
    int i = blockIdx.x * 256 + tid;
    int v = (i < N_NODES) ? counts[i] : 0;
    s[tid] = v;
    __syncthreads();
    for (int off = 1; off < 256; off <<= 1) {
        int t = (tid >= off) ? s[tid - off] : 0;
        __syncthreads();
        s[tid] += t;
        __syncthreads();
    }
    if (i < N_NODES) row_start[i] = s[tid] - v;  // exclusive
    if (tid == 255) bsum[blockIdx.x] = s[255];
}

__global__ __launch_bounds__(256)
void scan_bsums(int* __restrict__ bsum) {
    __shared__ int s[256];
    int tid = threadIdx.x;
    int v = (tid < NB_SCAN) ? bsum[tid] : 0;
    s[tid] = v;
    __syncthreads();
    for (int off = 1; off < 256; off <<= 1) {
        int t = (tid >= off) ? s[tid - off] : 0;
        __syncthreads();
        s[tid] += t;
        __syncthreads();
    }
    if (tid < NB_SCAN) bsum[tid] = s[tid] - v;  // exclusive
}

// finalize row_start, init cursor, compute dinv
__global__ void scan_fixup(int* __restrict__ row_start, const int* __restrict__ bsum,
                           int* __restrict__ cursor, const int* __restrict__ counts,
                           float* __restrict__ dinv) {
    int i = blockIdx.x * blockDim.x + threadIdx.x;
    if (i < N_NODES) {
        int rs = row_start[i] + bsum[i >> 8];
        row_start[i] = rs;
        cursor[i] = rs;
        dinv[i] = rsqrtf(1.0f + (float)counts[i]);  // +1 self-loop
    }
    if (i == 0) row_start[N_NODES] = N_EDGES;
}

__global__ void csr_fill(const int* __restrict__ ei, int* __restrict__ cursor,
                         const float* __restrict__ dinv, int* __restrict__ edge_src,
                         float* __restrict__ edge_w) {
    int e = blockIdx.x * blockDim.x + threadIdx.x;
    if (e < N_EDGES) {
        int r = ei[e];
        int c = ei[N_EDGES + e];
        int pos = atomicAdd(&cursor[c], 1);
        edge_src[pos] = r;
        edge_w[pos] = dinv[r] * dinv[c];
    }
}

// ---------------- dense GEMM: Y[n][OUT] = X[n][128] @ W[128][OUT] (+bias) ----------------

template <int OUT, bool ADD_BIAS>
__global__ __launch_bounds__(256)
void gemm128(const float* __restrict__ X, const float* __restrict__ W,
             const float* __restrict__ bias, float* __restrict__ Y, int n) {
    constexpr int ROWS = 32;
    __shared__ float Wl[128 * OUT];
    __shared__ float Xl[ROWS * 128];
    const int tid = threadIdx.x;
    const int r0 = blockIdx.x * ROWS;

    for (int i = tid; i < 128 * OUT; i += 256) Wl[i] = W[i];
    for (int i = tid; i < ROWS * 128; i += 256) {
        int r = r0 + (i >> 7);
        Xl[i] = (r < n) ? X[r0 * 128 + i] : 0.0f;
    }
    __syncthreads();

    constexpr int RG = 256 / OUT;
    constexpr int PR = ROWS / RG;
    const int colc = tid % OUT;
    const int rb = tid / OUT;

    float acc[PR];
#pragma unroll
    for (int i = 0; i < PR; i++) acc[i] = 0.0f;

    for (int k = 0; k < 128; k++) {
        float wv = Wl[k * OUT + colc];
#pragma unroll
        for (int i = 0; i < PR; i++) acc[i] += Xl[(rb + i * RG) * 128 + k] * wv;
    }

    float bv = ADD_BIAS ? bias[colc] : 0.0f;
#pragma unroll
    for (int i = 0; i < PR; i++) {
        int r = r0 + rb + i * RG;
        if (r < n) Y[r * OUT + colc] = acc[i] + bv;
    }
}

// ---------------- fused aggregation: self-loop + gather-sum + bias + relu ----------------

template <bool RELU>
__global__ __launch_bounds__(256)
void aggregate(const float* __restrict__ t, const int* __restrict__ row_start,
               const int* __restrict__ edge_src, const float* __restrict__ edge_w,
               const float* __restrict__ dinv, const float* __restrict__ bias,
               float* __restrict__ out) {
    const int tid = threadIdx.x;
    const int node = blockIdx.x * 2 + (tid >> 7);
    const int f = tid & 127;
    if (node >= N_NODES) return;

    float d = dinv[node];
    float acc = t[node * HID + f] * d * d;  // self-loop

    int k = row_start[node];
    const int k1 = row_start[node + 1];
    for (; k + 4 <= k1; k += 4) {
        int s0 = edge_src[k], s1 = edge_src[k + 1], s2 = edge_src[k + 2], s3 = edge_src[k + 3];
        float w0 = edge_w[k], w1 = edge_w[k + 1], w2 = edge_w[k + 2], w3 = edge_w[k + 3];
        float v0 = t[s0 * HID + f], v1 = t[s1 * HID + f];
        float v2 = t[s2 * HID + f], v3 = t[s3 * HID + f];
        acc += v0 * w0;
        acc += v1 * w1;
        acc += v2 * w2;
        acc += v3 * w3;
    }
    for (; k < k1; k++) acc += t[edge_src[k] * HID + f] * edge_w[k];

    float v = acc + bias[f];
    out[node * HID + f] = RELU ? fmaxf(v, 0.0f) : v;
}

// ---------------- mean pool ----------------

__global__ __launch_bounds__(256)
void mean_partial(const float* __restrict__ P, float* __restrict__ sum) {
    __shared__ float red[256];
    const int tid = threadIdx.x;
    const int c = tid & 63;
    const int grp = tid >> 6;
    float acc = 0.0f;
    for (int r = blockIdx.x * 4 + grp; r < N_NODES; r += gridDim.x * 4)
        acc += P[r * OUT_CH + c];
    red[tid] = acc;
    __syncthreads();
    if (grp == 0) {
        float s = red[c] + red[64 + c] + red[128 + c] + red[192 + c];
        atomicAdd(&sum[c], s);
    }
}

__global__ void mean_final(const float* __restrict__ sum, float* __restrict__ out) {
    int j = threadIdx.x;
    if (j < OUT_CH) out[N_NODES * OUT_CH + j] = sum[j] * (1.0f / N_NODES);
}

// ---------------- launch ----------------

extern "C" void kernel_launch(void* const* d_in, const int* in_sizes, int n_in,
                              void* d_out, int out_size, void* d_ws, size_t ws_size,
                              hipStream_t stream) {
    const float* x  = (const float*)d_in[0];
    const int* ei   = (const int*)d_in[1];   // int32 on device
    const float* W1 = (const float*)d_in[2];
    const float* b1 = (const float*)d_in[3];
    const float* W2 = (const float*)d_in[4];
    const float* b2 = (const float*)d_in[5];
    const float* W3 = (const float*)d_in[6];
    const float* b3 = (const float*)d_in[7];
    const float* Wo = (const float*)d_in[8];
    const float* bo = (const float*)d_in[9];
    float* out = (float*)d_out;

    char* ws = (char*)d_ws;
    auto take = [&](size_t bytes) {
        char* p = ws;
        ws += (bytes + 255) & ~size_t(255);
        return (void*)p;
    };
    int*   counts    = (int*)take((size_t)N_NODES * 4);
    int*   row_start = (int*)take((size_t)(N_NODES + 1) * 4);
    int*   bsum      = (int*)take((size_t)NB_SCAN * 4);
    int*   cursor    = (int*)take((size_t)N_NODES * 4);
    float* dinv      = (float*)take((size_t)N_NODES * 4);
    int*   edge_src  = (int*)take((size_t)N_EDGES * 4);
    float* edge_w    = (float*)take((size_t)N_EDGES * 4);
    float* sum       = (float*)take(OUT_CH * 4);
    float* hA        = (float*)take((size_t)N_NODES * HID * 4);
    float* hB        = (float*)take((size_t)N_NODES * HID * 4);

    const int BS = 256;
    const int gN    = (N_NODES + BS - 1) / BS;
    const int gE    = (N_EDGES + BS - 1) / BS;
    const int gGemm = (N_NODES + 31) / 32;
    const int gAgg  = (N_NODES + 1) / 2;

    // CSR build
    prep_init<<<gN, BS, 0, stream>>>(counts, sum);
    count_edges<<<gE, BS, 0, stream>>>(ei, counts);
    scan_blocks<<<NB_SCAN, BS, 0, stream>>>(counts, row_start, bsum);
    scan_bsums<<<1, BS, 0, stream>>>(bsum);
    scan_fixup<<<gN, BS, 0, stream>>>(row_start, bsum, cursor, counts, dinv);
    csr_fill<<<gE, BS, 0, stream>>>(ei, cursor, dinv, edge_src, edge_w);

    const float* hin = x;
    const float* Ws[3] = {W1, W2, W3};
    const float* bs[3] = {b1, b2, b3};
    for (int layer = 0; layer < 3; layer++) {
        gemm128<HID, false><<<gGemm, BS, 0, stream>>>(hin, Ws[layer], nullptr, hA, N_NODES);
        aggregate<true><<<gAgg, BS, 0, stream>>>(hA, row_start, edge_src, edge_w, dinv,
                                                 bs[layer], hB);
        hin = hB;
    }

    gemm128<OUT_CH, true><<<gGemm, BS, 0, stream>>>(hB, Wo, bo, out, N_NODES);
    mean_partial<<<256, BS, 0, stream>>>(out, sum);
    mean_final<<<1, 64, 0, stream>>>(sum, out);
}

// Round 5
// 420.713 us; speedup vs baseline: 3.3183x; 1.3423x over previous
//
#include <hip/hip_runtime.h>

#define N_NODES 50000
#define N_EDGES 800000
#define HID 128
#define OUT_CH 64
#define NB_SCAN 196   // ceil(50000/256)

// ---------------- CSR construction ----------------

__global__ void prep_init(int* __restrict__ counts, float* __restrict__ sum) {
    int i = blockIdx.x * blockDim.x + threadIdx.x;
    if (i < N_NODES) counts[i] = 0;
    if (i < OUT_CH) sum[i] = 0.0f;
}

__global__ void count_edges(const int* __restrict__ ei, int* __restrict__ counts) {
    int e = blockIdx.x * blockDim.x + threadIdx.x;
    if (e < N_EDGES) atomicAdd(&counts[ei[N_EDGES + e]], 1);  // target
}

__global__ __launch_bounds__(256)
void scan_blocks(const int* __restrict__ counts, int* __restrict__ row_start,
                 int* __restrict__ bsum) {
    __shared__ int s[256];
    int tid = threadIdx.x;
    int i = blockIdx.x * 256 + tid;
    int v = (i < N_NODES) ? counts[i] : 0;
    s[tid] = v;
    __syncthreads();
    for (int off = 1; off < 256; off <<= 1) {
        int t = (tid >= off) ? s[tid - off] : 0;
        __syncthreads();
        s[tid] += t;
        __syncthreads();
    }
    if (i < N_NODES) row_start[i] = s[tid] - v;  // exclusive
    if (tid == 255) bsum[blockIdx.x] = s[255];
}

__global__ __launch_bounds__(256)
void scan_bsums(int* __restrict__ bsum) {
    __shared__ int s[256];
    int tid = threadIdx.x;
    int v = (tid < NB_SCAN) ? bsum[tid] : 0;
    s[tid] = v;
    __syncthreads();
    for (int off = 1; off < 256; off <<= 1) {
        int t = (tid >= off) ? s[tid - off] : 0;
        __syncthreads();
        s[tid] += t;
        __syncthreads();
    }
    if (tid < NB_SCAN) bsum[tid] = s[tid] - v;  // exclusive
}

__global__ void scan_fixup(int* __restrict__ row_start, const int* __restrict__ bsum,
                           int* __restrict__ cursor, const int* __restrict__ counts,
                           float* __restrict__ dinv) {
    int i = blockIdx.x * blockDim.x + threadIdx.x;
    if (i < N_NODES) {
        int rs = row_start[i] + bsum[i >> 8];
        row_start[i] = rs;
        cursor[i] = rs;
        dinv[i] = rsqrtf(1.0f + (float)counts[i]);  // +1 self-loop
    }
    if (i == 0) row_start[N_NODES] = N_EDGES;
}

__global__ void csr_fill(const int* __restrict__ ei, int* __restrict__ cursor,
                         const float* __restrict__ dinv, int* __restrict__ edge_src,
                         float* __restrict__ edge_w) {
    int e = blockIdx.x * blockDim.x + threadIdx.x;
    if (e < N_EDGES) {
        int r = ei[e];
        int c = ei[N_EDGES + e];
        int pos = atomicAdd(&cursor[c], 1);
        edge_src[pos] = r;
        edge_w[pos] = dinv[r] * dinv[c];
    }
}

// ---------------- register-tiled GEMM: Y[n][OUT] = X[n][128] @ W[128][OUT] ----------------
// 64-row x OUT-col tile per 256-thread block; K staged in 32-wide chunks.
// Inner loop: 1 float4 W read + PR/4 float4 X reads feed PR*4 FMAs.

template <int OUT, bool ADD_BIAS>
__global__ __launch_bounds__(256)
void gemm_rt(const float* __restrict__ X, const float* __restrict__ W,
             const float* __restrict__ bias, float* __restrict__ Y, int n) {
    constexpr int CG  = OUT / 4;    // col groups per row of threads (32 or 16)
    constexpr int RG  = 256 / CG;   // row groups (8 or 16)
    constexpr int PR  = 64 / RG;    // rows per thread (8 or 4)
    constexpr int F4  = PR / 4;     // float4 X reads per thread per k (2 or 1)
    constexpr int XLD = 68;         // padded LDS row stride (floats), 17 float4

    __shared__ __align__(16) float Wl[32 * OUT];
    __shared__ __align__(16) float XlT[32 * XLD];

    const int tid = threadIdx.x;
    const int cx = tid % CG;        // -> cols 4*cx .. 4*cx+3
    const int ry = tid / CG;        // -> rows ry*PR .. ry*PR+PR-1
    const int r0 = blockIdx.x * 64;

    float4 acc[PR];
#pragma unroll
    for (int j = 0; j < PR; j++) acc[j] = make_float4(0.f, 0.f, 0.f, 0.f);

    const float4* XlT4 = (const float4*)XlT;

    for (int k0 = 0; k0 < 128; k0 += 32) {
        __syncthreads();
        for (int t = tid; t < 32 * OUT; t += 256) Wl[t] = W[k0 * OUT + t];
        for (int t = tid; t < 64 * 32; t += 256) {
            int r = t >> 5, kk = t & 31;
            XlT[kk * XLD + r] =
                (r0 + r < n) ? X[(size_t)(r0 + r) * 128 + k0 + kk] : 0.0f;
        }
        __syncthreads();

#pragma unroll 4
        for (int kk = 0; kk < 32; kk++) {
            const float4 w = *(const float4*)&Wl[kk * OUT + cx * 4];
#pragma unroll
            for (int q = 0; q < F4; q++) {
                float4 xq = XlT4[kk * (XLD / 4) + F4 * ry + q];
                float xv[4] = {xq.x, xq.y, xq.z, xq.w};
#pragma unroll
                for (int jj = 0; jj < 4; jj++) {
                    int j = q * 4 + jj;
                    acc[j].x += xv[jj] * w.x;
                    acc[j].y += xv[jj] * w.y;
                    acc[j].z += xv[jj] * w.z;
                    acc[j].w += xv[jj] * w.w;
                }
            }
        }
    }

    float4 bv = make_float4(0.f, 0.f, 0.f, 0.f);
    if (ADD_BIAS) bv = *(const float4*)&bias[cx * 4];
#pragma unroll
    for (int j = 0; j < PR; j++) {
        int r = r0 + ry * PR + j;
        if (r < n) {
            float4 o;
            o.x = acc[j].x + bv.x;
            o.y = acc[j].y + bv.y;
            o.z = acc[j].z + bv.z;
            o.w = acc[j].w + bv.w;
            *(float4*)&Y[(size_t)r * OUT + cx * 4] = o;
        }
    }
}

// ---------------- fused aggregation: self-loop + gather-sum + bias + relu ----------------
// One node per 32 lanes, 4 features (float4) per lane.

template <bool RELU>
__global__ __launch_bounds__(256)
void aggregate4(const float* __restrict__ t, const int* __restrict__ row_start,
                const int* __restrict__ edge_src, const float* __restrict__ edge_w,
                const float* __restrict__ dinv, const float* __restrict__ bias,
                float* __restrict__ out) {
    const int tid = threadIdx.x;
    const int node = blockIdx.x * 8 + (tid >> 5);
    const int f4 = tid & 31;   // float4 index: features 4*f4..4*f4+3
    if (node >= N_NODES) return;

    const float4* t4 = (const float4*)t;
    const float d = dinv[node];
    float4 sv = t4[(size_t)node * 32 + f4];
    float4 acc;
    acc.x = sv.x * d * d;
    acc.y = sv.y * d * d;
    acc.z = sv.z * d * d;
    acc.w = sv.w * d * d;

    int k = row_start[node];
    const int k1 = row_start[node + 1];
    for (; k + 4 <= k1; k += 4) {
        int s0 = edge_src[k], s1 = edge_src[k + 1];
        int s2 = edge_src[k + 2], s3 = edge_src[k + 3];
        float w0 = edge_w[k], w1 = edge_w[k + 1];
        float w2 = edge_w[k + 2], w3 = edge_w[k + 3];
        float4 v0 = t4[(size_t)s0 * 32 + f4];
        float4 v1 = t4[(size_t)s1 * 32 + f4];
        float4 v2 = t4[(size_t)s2 * 32 + f4];
        float4 v3 = t4[(size_t)s3 * 32 + f4];
        acc.x += v0.x * w0; acc.y += v0.y * w0; acc.z += v0.z * w0; acc.w += v0.w * w0;
        acc.x += v1.x * w1; acc.y += v1.y * w1; acc.z += v1.z * w1; acc.w += v1.w * w1;
        acc.x += v2.x * w2; acc.y += v2.y * w2; acc.z += v2.z * w2; acc.w += v2.w * w2;
        acc.x += v3.x * w3; acc.y += v3.y * w3; acc.z += v3.z * w3; acc.w += v3.w * w3;
    }
    for (; k < k1; k++) {
        int s = edge_src[k];
        float w = edge_w[k];
        float4 v = t4[(size_t)s * 32 + f4];
        acc.x += v.x * w; acc.y += v.y * w; acc.z += v.z * w; acc.w += v.w * w;
    }

    float4 b = ((const float4*)bias)[f4];
    acc.x += b.x; acc.y += b.y; acc.z += b.z; acc.w += b.w;
    if (RELU) {
        acc.x = fmaxf(acc.x, 0.f); acc.y = fmaxf(acc.y, 0.f);
        acc.z = fmaxf(acc.z, 0.f); acc.w = fmaxf(acc.w, 0.f);
    }
    ((float4*)out)[(size_t)node * 32 + f4] = acc;
}

// ---------------- mean pool ----------------

__global__ __launch_bounds__(256)
void mean_partial(const float* __restrict__ P, float* __restrict__ sum) {
    __shared__ float red[256];
    const int tid = threadIdx.x;
    const int c = tid & 63;
    const int grp = tid >> 6;
    float acc = 0.0f;
    for (int r = blockIdx.x * 4 + grp; r < N_NODES; r += gridDim.x * 4)
        acc += P[r * OUT_CH + c];
    red[tid] = acc;
    __syncthreads();
    if (grp == 0) {
        float s = red[c] + red[64 + c] + red[128 + c] + red[192 + c];
        atomicAdd(&sum[c], s);
    }
}

__global__ void mean_final(const float* __restrict__ sum, float* __restrict__ out) {
    int j = threadIdx.x;
    if (j < OUT_CH) out[N_NODES * OUT_CH + j] = sum[j] * (1.0f / N_NODES);
}

// ---------------- launch ----------------

extern "C" void kernel_launch(void* const* d_in, const int* in_sizes, int n_in,
                              void* d_out, int out_size, void* d_ws, size_t ws_size,
                              hipStream_t stream) {
    const float* x  = (const float*)d_in[0];
    const int* ei   = (const int*)d_in[1];   // int32 on device
    const float* W1 = (const float*)d_in[2];
    const float* b1 = (const float*)d_in[3];
    const float* W2 = (const float*)d_in[4];
    const float* b2 = (const float*)d_in[5];
    const float* W3 = (const float*)d_in[6];
    const float* b3 = (const float*)d_in[7];
    const float* Wo = (const float*)d_in[8];
    const float* bo = (const float*)d_in[9];
    float* out = (float*)d_out;

    char* ws = (char*)d_ws;
    auto take = [&](size_t bytes) {
        char* p = ws;
        ws += (bytes + 255) & ~size_t(255);
        return (void*)p;
    };
    int*   counts    = (int*)take((size_t)N_NODES * 4);
    int*   row_start = (int*)take((size_t)(N_NODES + 1) * 4);
    int*   bsum      = (int*)take((size_t)NB_SCAN * 4);
    int*   cursor    = (int*)take((size_t)N_NODES * 4);
    float* dinv      = (float*)take((size_t)N_NODES * 4);
    int*   edge_src  = (int*)take((size_t)N_EDGES * 4);
    float* edge_w    = (float*)take((size_t)N_EDGES * 4);
    float* sum       = (float*)take(OUT_CH * 4);
    float* hA        = (float*)take((size_t)N_NODES * HID * 4);
    float* hB        = (float*)take((size_t)N_NODES * HID * 4);

    const int BS = 256;
    const int gN    = (N_NODES + BS - 1) / BS;
    const int gE    = (N_EDGES + BS - 1) / BS;
    const int gGemm = (N_NODES + 63) / 64;
    const int gAgg  = (N_NODES + 7) / 8;

    // CSR build
    prep_init<<<gN, BS, 0, stream>>>(counts, sum);
    count_edges<<<gE, BS, 0, stream>>>(ei, counts);
    scan_blocks<<<NB_SCAN, BS, 0, stream>>>(counts, row_start, bsum);
    scan_bsums<<<1, BS, 0, stream>>>(bsum);
    scan_fixup<<<gN, BS, 0, stream>>>(row_start, bsum, cursor, counts, dinv);
    csr_fill<<<gE, BS, 0, stream>>>(ei, cursor, dinv, edge_src, edge_w);

    const float* hin = x;
    const float* Ws[3] = {W1, W2, W3};
    const float* bs[3] = {b1, b2, b3};
    for (int layer = 0; layer < 3; layer++) {
        gemm_rt<HID, false><<<gGemm, BS, 0, stream>>>(hin, Ws[layer], nullptr, hA, N_NODES);
        aggregate4<true><<<gAgg, BS, 0, stream>>>(hA, row_start, edge_src, edge_w, dinv,
                                                  bs[layer], hB);
        hin = hB;
    }

    gemm_rt<OUT_CH, true><<<gGemm, BS, 0, stream>>>(hB, Wo, bo, out, N_NODES);
    mean_partial<<<256, BS, 0, stream>>>(out, sum);
    mean_final<<<1, 64, 0, stream>>>(sum, out);
}

// Round 6
// 353.659 us; speedup vs baseline: 3.9474x; 1.1896x over previous
//
#include <hip/hip_runtime.h>
#include <hip/hip_fp16.h>

#define N_NODES 50000
#define N_EDGES 800000
#define HID 128
#define OUT_CH 64
#define NB_SCAN 196   // ceil(50000/256)

// ---------------- CSR construction ----------------

__global__ void prep_init(int* __restrict__ counts, float* __restrict__ sum) {
    int i = blockIdx.x * blockDim.x + threadIdx.x;
    if (i < N_NODES) counts[i] = 0;
    if (i < OUT_CH) sum[i] = 0.0f;
}

__global__ void count_edges(const int* __restrict__ ei, int* __restrict__ counts) {
    int e = blockIdx.x * blockDim.x + threadIdx.x;
    if (e < N_EDGES) atomicAdd(&counts[ei[N_EDGES + e]], 1);  // target
}

__global__ __launch_bounds__(256)
void scan_blocks(const int* __restrict__ counts, int* __restrict__ row_start,
                 int* __restrict__ bsum) {
    __shared__ int s[256];
    int tid = threadIdx.x;
    int i = blockIdx.x * 256 + tid;
    int v = (i < N_NODES) ? counts[i] : 0;
    s[tid] = v;
    __syncthreads();
    for (int off = 1; off < 256; off <<= 1) {
        int t = (tid >= off) ? s[tid - off] : 0;
        __syncthreads();
        s[tid] += t;
        __syncthreads();
    }
    if (i < N_NODES) row_start[i] = s[tid] - v;  // exclusive
    if (tid == 255) bsum[blockIdx.x] = s[255];
}

__global__ __launch_bounds__(256)
void scan_bsums(int* __restrict__ bsum) {
    __shared__ int s[256];
    int tid = threadIdx.x;
    int v = (tid < NB_SCAN) ? bsum[tid] : 0;
    s[tid] = v;
    __syncthreads();
    for (int off = 1; off < 256; off <<= 1) {
        int t = (tid >= off) ? s[tid - off] : 0;
        __syncthreads();
        s[tid] += t;
        __syncthreads();
    }
    if (tid < NB_SCAN) bsum[tid] = s[tid] - v;  // exclusive
}

__global__ void scan_fixup(int* __restrict__ row_start, const int* __restrict__ bsum,
                           int* __restrict__ cursor, const int* __restrict__ counts,
                           float* __restrict__ dinv) {
    int i = blockIdx.x * blockDim.x + threadIdx.x;
    if (i < N_NODES) {
        int rs = row_start[i] + bsum[i >> 8];
        row_start[i] = rs;
        cursor[i] = rs;
        dinv[i] = rsqrtf(1.0f + (float)counts[i]);  // +1 self-loop
    }
    if (i == 0) row_start[N_NODES] = N_EDGES;
}

// edge record: {src, bits(norm)} packed in int2, destination-sorted
__global__ void csr_fill(const int* __restrict__ ei, int* __restrict__ cursor,
                         const float* __restrict__ dinv, int2* __restrict__ erec) {
    int e = blockIdx.x * blockDim.x + threadIdx.x;
    if (e < N_EDGES) {
        int r = ei[e];
        int c = ei[N_EDGES + e];
        int pos = atomicAdd(&cursor[c], 1);
        erec[pos] = make_int2(r, __float_as_int(dinv[r] * dinv[c]));
    }
}

// ---------------- register-tiled GEMM: Y[n][OUT] = X[n][128] @ W[128][OUT] ----------------
// 64-row x OUT-col tile per 256-thread block; K staged in 32-wide chunks.
// HALF_OUT: write fp16 (for the pre-aggregation buffer), else fp32.

template <int OUT, bool ADD_BIAS, bool HALF_OUT>
__global__ __launch_bounds__(256)
void gemm_rt(const float* __restrict__ X, const float* __restrict__ W,
             const float* __restrict__ bias, void* __restrict__ Yv, int n) {
    constexpr int CG  = OUT / 4;    // col groups (32 or 16)
    constexpr int RG  = 256 / CG;   // row groups (8 or 16)
    constexpr int PR  = 64 / RG;    // rows per thread (8 or 4)
    constexpr int F4  = PR / 4;     // float4 X reads per thread per k (2 or 1)
    constexpr int XLD = 68;         // padded LDS row stride (floats)

    __shared__ __align__(16) float Wl[32 * OUT];
    __shared__ __align__(16) float XlT[32 * XLD];

    const int tid = threadIdx.x;
    const int cx = tid % CG;
    const int ry = tid / CG;
    const int r0 = blockIdx.x * 64;

    float4 acc[PR];
#pragma unroll
    for (int j = 0; j < PR; j++) acc[j] = make_float4(0.f, 0.f, 0.f, 0.f);

    const float4* XlT4 = (const float4*)XlT;

    for (int k0 = 0; k0 < 128; k0 += 32) {
        __syncthreads();
        for (int t = tid; t < 32 * OUT; t += 256) Wl[t] = W[k0 * OUT + t];
        for (int t = tid; t < 64 * 32; t += 256) {
            int r = t >> 5, kk = t & 31;
            XlT[kk * XLD + r] =
                (r0 + r < n) ? X[(size_t)(r0 + r) * 128 + k0 + kk] : 0.0f;
        }
        __syncthreads();

#pragma unroll 4
        for (int kk = 0; kk < 32; kk++) {
            const float4 w = *(const float4*)&Wl[kk * OUT + cx * 4];
#pragma unroll
            for (int q = 0; q < F4; q++) {
                float4 xq = XlT4[kk * (XLD / 4) + F4 * ry + q];
                float xv[4] = {xq.x, xq.y, xq.z, xq.w};
#pragma unroll
                for (int jj = 0; jj < 4; jj++) {
                    int j = q * 4 + jj;
                    acc[j].x += xv[jj] * w.x;
                    acc[j].y += xv[jj] * w.y;
                    acc[j].z += xv[jj] * w.z;
                    acc[j].w += xv[jj] * w.w;
                }
            }
        }
    }

    float4 bv = make_float4(0.f, 0.f, 0.f, 0.f);
    if (ADD_BIAS) bv = *(const float4*)&bias[cx * 4];
#pragma unroll
    for (int j = 0; j < PR; j++) {
        int r = r0 + ry * PR + j;
        if (r < n) {
            float4 o;
            o.x = acc[j].x + bv.x;
            o.y = acc[j].y + bv.y;
            o.z = acc[j].z + bv.z;
            o.w = acc[j].w + bv.w;
            if constexpr (HALF_OUT) {
                union { __half2 h2[2]; int2 i2; } u;
                u.h2[0] = __floats2half2_rn(o.x, o.y);
                u.h2[1] = __floats2half2_rn(o.z, o.w);
                *(int2*)((__half*)Yv + (size_t)r * OUT + cx * 4) = u.i2;
            } else {
                *(float4*)((float*)Yv + (size_t)r * OUT + cx * 4) = o;
            }
        }
    }
}

// ---------------- fused aggregation: self-loop + gather-sum + bias + relu ----------------
// One node per 32 lanes, 4 fp16 features (int2 = 8B) per lane; f32 accumulate.

__global__ __launch_bounds__(256)
void aggregate_h(const __half* __restrict__ t, const int* __restrict__ row_start,
                 const int2* __restrict__ erec, const float* __restrict__ dinv,
                 const float* __restrict__ bias, float* __restrict__ out) {
    const int tid = threadIdx.x;
    const int node = blockIdx.x * 8 + (tid >> 5);
    const int f4 = tid & 31;   // features 4*f4 .. 4*f4+3
    if (node >= N_NODES) return;

    const int2* t2 = (const int2*)t;

    const float d = dinv[node];
    int2 sg = t2[(size_t)node * 32 + f4];
    float2 slo = __half22float2(*(__half2*)&sg.x);
    float2 shi = __half22float2(*(__half2*)&sg.y);
    float4 acc;
    acc.x = slo.x * d * d;
    acc.y = slo.y * d * d;
    acc.z = shi.x * d * d;
    acc.w = shi.y * d * d;

    int k = row_start[node];
    const int k1 = row_start[node + 1];
    for (; k + 8 <= k1; k += 8) {
        int2 rec[8];
#pragma unroll
        for (int u = 0; u < 8; u++) rec[u] = erec[k + u];
        int2 g[8];
#pragma unroll
        for (int u = 0; u < 8; u++) g[u] = t2[(size_t)rec[u].x * 32 + f4];
#pragma unroll
        for (int u = 0; u < 8; u++) {
            float w = __int_as_float(rec[u].y);
            float2 lo = __half22float2(*(__half2*)&g[u].x);
            float2 hi = __half22float2(*(__half2*)&g[u].y);
            acc.x += lo.x * w;
            acc.y += lo.y * w;
            acc.z += hi.x * w;
            acc.w += hi.y * w;
        }
    }
    for (; k < k1; k++) {
        int2 rec = erec[k];
        float w = __int_as_float(rec.y);
        int2 g = t2[(size_t)rec.x * 32 + f4];
        float2 lo = __half22float2(*(__half2*)&g.x);
        float2 hi = __half22float2(*(__half2*)&g.y);
        acc.x += lo.x * w;
        acc.y += lo.y * w;
        acc.z += hi.x * w;
        acc.w += hi.y * w;
    }

    float4 b = ((const float4*)bias)[f4];
    acc.x = fmaxf(acc.x + b.x, 0.f);
    acc.y = fmaxf(acc.y + b.y, 0.f);
    acc.z = fmaxf(acc.z + b.z, 0.f);
    acc.w = fmaxf(acc.w + b.w, 0.f);
    ((float4*)out)[(size_t)node * 32 + f4] = acc;
}

// ---------------- mean pool ----------------

__global__ __launch_bounds__(256)
void mean_partial(const float* __restrict__ P, float* __restrict__ sum) {
    __shared__ float red[256];
    const int tid = threadIdx.x;
    const int c = tid & 63;
    const int grp = tid >> 6;
    float acc = 0.0f;
    for (int r = blockIdx.x * 4 + grp; r < N_NODES; r += gridDim.x * 4)
        acc += P[r * OUT_CH + c];
    red[tid] = acc;
    __syncthreads();
    if (grp == 0) {
        float s = red[c] + red[64 + c] + red[128 + c] + red[192 + c];
        atomicAdd(&sum[c], s);
    }
}

__global__ void mean_final(const float* __restrict__ sum, float* __restrict__ out) {
    int j = threadIdx.x;
    if (j < OUT_CH) out[N_NODES * OUT_CH + j] = sum[j] * (1.0f / N_NODES);
}

// ---------------- launch ----------------

extern "C" void kernel_launch(void* const* d_in, const int* in_sizes, int n_in,
                              void* d_out, int out_size, void* d_ws, size_t ws_size,
                              hipStream_t stream) {
    const float* x  = (const float*)d_in[0];
    const int* ei   = (const int*)d_in[1];   // int32 on device
    const float* W1 = (const float*)d_in[2];
    const float* b1 = (const float*)d_in[3];
    const float* W2 = (const float*)d_in[4];
    const float* b2 = (const float*)d_in[5];
    const float* W3 = (const float*)d_in[6];
    const float* b3 = (const float*)d_in[7];
    const float* Wo = (const float*)d_in[8];
    const float* bo = (const float*)d_in[9];
    float* out = (float*)d_out;

    char* ws = (char*)d_ws;
    auto take = [&](size_t bytes) {
        char* p = ws;
        ws += (bytes + 255) & ~size_t(255);
        return (void*)p;
    };
    int*    counts    = (int*)take((size_t)N_NODES * 4);
    int*    row_start = (int*)take((size_t)(N_NODES + 1) * 4);
    int*    bsum      = (int*)take((size_t)NB_SCAN * 4);
    int*    cursor    = (int*)take((size_t)N_NODES * 4);
    float*  dinv      = (float*)take((size_t)N_NODES * 4);
    int2*   erec      = (int2*)take((size_t)N_EDGES * 8);
    float*  sum       = (float*)take(OUT_CH * 4);
    __half* hA        = (__half*)take((size_t)N_NODES * HID * 2);
    float*  hB        = (float*)take((size_t)N_NODES * HID * 4);

    const int BS = 256;
    const int gN    = (N_NODES + BS - 1) / BS;
    const int gE    = (N_EDGES + BS - 1) / BS;
    const int gGemm = (N_NODES + 63) / 64;
    const int gAgg  = (N_NODES + 7) / 8;

    // CSR build
    prep_init<<<gN, BS, 0, stream>>>(counts, sum);
    count_edges<<<gE, BS, 0, stream>>>(ei, counts);
    scan_blocks<<<NB_SCAN, BS, 0, stream>>>(counts, row_start, bsum);
    scan_bsums<<<1, BS, 0, stream>>>(bsum);
    scan_fixup<<<gN, BS, 0, stream>>>(row_start, bsum, cursor, counts, dinv);
    csr_fill<<<gE, BS, 0, stream>>>(ei, cursor, dinv, erec);

    const float* hin = x;
    const float* Ws[3] = {W1, W2, W3};
    const float* bs[3] = {b1, b2, b3};
    for (int layer = 0; layer < 3; layer++) {
        gemm_rt<HID, false, true><<<gGemm, BS, 0, stream>>>(hin, Ws[layer], nullptr, hA, N_NODES);
        aggregate_h<<<gAgg, BS, 0, stream>>>(hA, row_start, erec, dinv, bs[layer], hB);
        hin = hB;
    }

    gemm_rt<OUT_CH, true, false><<<gGemm, BS, 0, stream>>>(hB, Wo, bo, out, N_NODES);
    mean_partial<<<256, BS, 0, stream>>>(out, sum);
    mean_final<<<1, 64, 0, stream>>>(sum, out);
}